// Round 1
// baseline (161.571 us; speedup 1.0000x reference)
//
#include <hip/hip_runtime.h>

// RankingLoss: B=16384 rows, D=1024 fp32, C=14 int32 labels -> scalar fp32.
//
// Phase 1 (latency-bound fix): block = 4 waves covering ONE 4-row output
// group; wave w owns D-quarter w. Each wave issues its 10 float4 loads
// (rows r0..r0+4 x {zi,zt}) in ONE batch -> single vmcnt stall per wave,
// and the grid is 4096 blocks (4x more waves than before) so the CU
// scheduler backfills stalled SIMDs with fresh load batches.
// Cross-wave dot combine via 192B LDS; margins via 2 ballots in wave 0
// with label loads hoisted to kernel start (latency hidden under dots).
// XCD-aware swizzle keeps consecutive row-groups on one XCD so the
// overlap row r0+4 is L2-local. Phase 2 reduces 4096 partials.

constexpr int D   = 1024;
constexpr int C   = 14;
constexpr int RPB = 4;   // output rows per block (one 4-row group)
constexpr int WPB = 4;   // waves per block; wave w covers D-quarter w

__device__ __forceinline__ float dot4(const float4 x, const float4 y) {
    return x.x * y.x + x.y * y.y + x.z * y.z + x.w * y.w;
}

__global__ __launch_bounds__(256) void rank_phase1(
    const float* __restrict__ zi, const float* __restrict__ zt,
    const int* __restrict__ labels, float* __restrict__ partial, int B)
{
    const int wave = threadIdx.x >> 6;
    const int lane = threadIdx.x & 63;

    // Bijective XCD swizzle (gridDim.x % 8 == 0): consecutive work-groups
    // stay on one XCD so block wg and wg+1 share row r0+4 in that L2.
    const int nwg = gridDim.x;
    const int wg  = (blockIdx.x & 7) * (nwg >> 3) + (blockIdx.x >> 3);

    const int r0 = wg * RPB;
    const int M  = B - 1;  // B is a power of two

    // Wave w reads float4 index [wave*64 + lane] of each row = quarter w.
    const int idx = (wave << 6) + lane;

    // Early label loads (wave 0 only); ballots consumed after syncthreads.
    int lx = 0, lo = 0;
    {
        const int kk = lane >> 4, c = lane & 15;
        if (wave == 0 && c < C) {
            const int ra = (r0 + kk)     & M;
            const int rb = (r0 + kk + 1) & M;
            const int li = labels[(size_t)ra * C + c];
            const int lj = labels[(size_t)rb * C + c];
            lx = li ^ lj;
            lo = li | lj;
        }
    }

    // Batch ALL 10 loads (5 rows x 2 tensors, one quarter each), then dots.
    float4 a[RPB + 1], b[RPB + 1];
    #pragma unroll
    for (int k = 0; k <= RPB; ++k) {
        const int r = (r0 + k) & M;
        a[k] = ((const float4*)(zi + (size_t)r * D))[idx];
        b[k] = ((const float4*)(zt + (size_t)r * D))[idx];
    }

    float v[12];
    #pragma unroll
    for (int k = 0; k < RPB; ++k) {
        v[k]     = dot4(a[k],     b[k]);      // paired   dot(zi[k],  zt[k])
        v[4 + k] = dot4(a[k + 1], b[k]);      // imp_img  dot(zi[k+1],zt[k])
        v[8 + k] = dot4(b[k + 1], a[k]);      // imp_txt  dot(zt[k+1],zi[k])
    }

    // Wave-reduce the 12 quarter-dot partials (independent chains pipeline).
    #pragma unroll
    for (int off = 32; off > 0; off >>= 1) {
        #pragma unroll
        for (int i = 0; i < 12; ++i) v[i] += __shfl_down(v[i], off, 64);
    }

    __shared__ float red[WPB][12];
    if (lane == 0) {
        #pragma unroll
        for (int i = 0; i < 12; ++i) red[wave][i] = v[i];
    }
    __syncthreads();

    if (wave == 0) {
        const unsigned long long bx = __ballot(lx != 0);
        const unsigned long long bo = __ballot(lo != 0);
        if (lane == 0) {
            float local = 0.f;
            #pragma unroll
            for (int k = 0; k < RPB; ++k) {
                const float p  = red[0][k]     + red[1][k]     + red[2][k]     + red[3][k];
                const float di = red[0][4 + k] + red[1][4 + k] + red[2][4 + k] + red[3][4 + k];
                const float dt = red[0][8 + k] + red[1][8 + k] + red[2][8 + k] + red[3][8 + k];
                const float dv = (float)__popcll((bx >> (16 * k)) & 0x3FFFull);
                const float nv = (float)__popcll((bo >> (16 * k)) & 0x3FFFull);
                const float m  = (dv == 0.f) ? 0.f : fmaxf(0.5f, dv / nv);
                local += fmaxf(di - p + m, 0.f) + fmaxf(dt - p + m, 0.f);
            }
            partial[wg] = local;
        }
    }
}

__global__ __launch_bounds__(256) void rank_phase2(
    const float* __restrict__ partial, float* __restrict__ out,
    int npart, float invB)
{
    float s = 0.f;
    for (int i = threadIdx.x; i < npart; i += 256) s += partial[i];
    #pragma unroll
    for (int off = 32; off > 0; off >>= 1) s += __shfl_down(s, off, 64);
    __shared__ float sm[4];
    if ((threadIdx.x & 63) == 0) sm[threadIdx.x >> 6] = s;
    __syncthreads();
    if (threadIdx.x == 0)
        out[0] = (sm[0] + sm[1] + sm[2] + sm[3]) * invB;
}

extern "C" void kernel_launch(void* const* d_in, const int* in_sizes, int n_in,
                              void* d_out, int out_size, void* d_ws, size_t ws_size,
                              hipStream_t stream) {
    const float* zi     = (const float*)d_in[0];
    const float* zt     = (const float*)d_in[1];
    const int*   labels = (const int*)d_in[2];
    float*       out    = (float*)d_out;
    float*       ws     = (float*)d_ws;

    const int B      = in_sizes[0] / D;  // 16384
    const int blocks = B / RPB;          // 4096

    rank_phase1<<<blocks, 256, 0, stream>>>(zi, zt, labels, ws, B);
    rank_phase2<<<1, 256, 0, stream>>>(ws, out, blocks, 1.0f / (float)B);
}

// Round 4
// 158.561 us; speedup vs baseline: 1.0190x; 1.0190x over previous
//
#include <hip/hip_runtime.h>

// RankingLoss: B=16384 rows, D=1024 fp32, C=14 int32 labels -> scalar fp32.
//
// Round 4 = round 3 resubmitted verbatim (container failed twice; kernel
// itself has no risky constructs - no atomics, no data-dependent loops).
// Change under test: traffic reduction. Block = 16 output rows; its 4 waves
// each own one D-quarter of ALL 17 data rows (overlap 17/16 = 1.06x vs
// 5/4 = 1.25x in round 1): 160 MB -> 136 MB of vector-load traffic.
// Chunk-pipelined loads (next chunk's 8 float4 loads issued before current
// chunk's FMAs) keep ~8-10 loads in flight per wave. Margins via 2 ballots
// per wave (4 rows each). Cross-wave combine via LDS; per-block partial ->
// d_ws; deterministic 1-block phase2. XCD-bijective swizzle (1024 % 8 == 0).

constexpr int D   = 1024;
constexpr int C   = 14;
constexpr int RPB = 16;  // output rows per block
constexpr int WPB = 4;   // waves per block; wave w covers D-quarter w

__device__ __forceinline__ float dot4(const float4 x, const float4 y) {
    return x.x * y.x + x.y * y.y + x.z * y.z + x.w * y.w;
}

__global__ __launch_bounds__(256) void rank_phase1(
    const float* __restrict__ zi, const float* __restrict__ zt,
    const int* __restrict__ labels, float* __restrict__ partial, int B)
{
    const int wave = threadIdx.x >> 6;
    const int lane = threadIdx.x & 63;

    // Bijective XCD swizzle (gridDim.x % 8 == 0).
    const int nwg = gridDim.x;
    const int wg  = (blockIdx.x & 7) * (nwg >> 3) + (blockIdx.x >> 3);

    const int r0  = wg * RPB;
    const int M   = B - 1;               // B is a power of two
    const int idx = (wave << 6) + lane;  // float4 index: wave w = quarter w

    __shared__ float red[WPB][48];
    __shared__ float mlds[RPB];

    // Label margins: wave w covers rows r0+4w..r0+4w+3 via 2 ballots;
    // lanes 0..3 each finalize one margin into LDS.
    {
        const int kk = lane >> 4, c = lane & 15;
        int lx = 0, lo = 0;
        if (c < C) {
            const int ra = (r0 + 4 * wave + kk) & M;
            const int rb = (ra + 1) & M;
            const int li = labels[(size_t)ra * C + c];
            const int lj = labels[(size_t)rb * C + c];
            lx = li ^ lj;
            lo = li | lj;
        }
        const unsigned long long bx = __ballot(lx != 0);
        const unsigned long long bo = __ballot(lo != 0);
        if (lane < 4) {
            const float dv = (float)__popcll((bx >> (16 * lane)) & 0x3FFFull);
            const float nv = (float)__popcll((bo >> (16 * lane)) & 0x3FFFull);
            mlds[4 * wave + lane] = (dv == 0.f) ? 0.f : fmaxf(0.5f, dv / nv);
        }
    }

    // v[k]=paired_k, v[16+k]=imp_img_k, v[32+k]=imp_txt_k  (k = 0..15)
    float v[48];
    #pragma unroll
    for (int i = 0; i < 48; ++i) v[i] = 0.f;

    // Chunk c covers data rows 4c..4c+4 (outputs 4c..4c+3); next chunk's 8
    // loads are issued before this chunk's FMAs. Boundary row rotates.
    float4 a[5], b[5], na[4], nb[4];
    #pragma unroll
    for (int k = 0; k < 5; ++k) {
        const int r = (r0 + k) & M;
        a[k] = ((const float4*)(zi + (size_t)r * D))[idx];
        b[k] = ((const float4*)(zt + (size_t)r * D))[idx];
    }

    #pragma unroll
    for (int cch = 0; cch < 4; ++cch) {
        if (cch < 3) {
            #pragma unroll
            for (int j = 0; j < 4; ++j) {
                const int r = (r0 + 4 * cch + 5 + j) & M;
                na[j] = ((const float4*)(zi + (size_t)r * D))[idx];
                nb[j] = ((const float4*)(zt + (size_t)r * D))[idx];
            }
        }
        #pragma unroll
        for (int k = 0; k < 4; ++k) {
            v[4 * cch + k]      += dot4(a[k],     b[k]);   // paired
            v[16 + 4 * cch + k] += dot4(a[k + 1], b[k]);   // imp_img
            v[32 + 4 * cch + k] += dot4(b[k + 1], a[k]);   // imp_txt
        }
        if (cch < 3) {
            a[0] = a[4]; b[0] = b[4];
            #pragma unroll
            for (int j = 0; j < 4; ++j) { a[j + 1] = na[j]; b[j + 1] = nb[j]; }
        }
    }

    // Wave-reduce 48 partials (independent chains pipeline across steps).
    #pragma unroll
    for (int off = 32; off > 0; off >>= 1) {
        #pragma unroll
        for (int i = 0; i < 48; ++i) v[i] += __shfl_down(v[i], off, 64);
    }
    if (lane == 0) {
        #pragma unroll
        for (int i = 0; i < 48; ++i) red[wave][i] = v[i];
    }
    __syncthreads();

    if (wave == 0 && lane < RPB) {
        float P = 0.f, I = 0.f, T = 0.f;
        #pragma unroll
        for (int w = 0; w < WPB; ++w) {
            P += red[w][lane];
            I += red[w][16 + lane];
            T += red[w][32 + lane];
        }
        const float m = mlds[lane];
        float local = fmaxf(I - P + m, 0.f) + fmaxf(T - P + m, 0.f);
        #pragma unroll
        for (int off = 8; off > 0; off >>= 1)
            local += __shfl_down(local, off, 16);
        if (lane == 0) partial[wg] = local;
    }
}

__global__ __launch_bounds__(256) void rank_phase2(
    const float* __restrict__ partial, float* __restrict__ out,
    int npart, float invB)
{
    float s = 0.f;
    for (int i = threadIdx.x; i < npart; i += 256) s += partial[i];
    #pragma unroll
    for (int off = 32; off > 0; off >>= 1) s += __shfl_down(s, off, 64);
    __shared__ float sm[4];
    if ((threadIdx.x & 63) == 0) sm[threadIdx.x >> 6] = s;
    __syncthreads();
    if (threadIdx.x == 0)
        out[0] = (sm[0] + sm[1] + sm[2] + sm[3]) * invB;
}

extern "C" void kernel_launch(void* const* d_in, const int* in_sizes, int n_in,
                              void* d_out, int out_size, void* d_ws, size_t ws_size,
                              hipStream_t stream) {
    const float* zi     = (const float*)d_in[0];
    const float* zt     = (const float*)d_in[1];
    const int*   labels = (const int*)d_in[2];
    float*       out    = (float*)d_out;
    float*       ws     = (float*)d_ws;

    const int B      = in_sizes[0] / D;  // 16384
    const int blocks = B / RPB;          // 1024

    rank_phase1<<<blocks, 256, 0, stream>>>(zi, zt, labels, ws, B);
    rank_phase2<<<1, 256, 0, stream>>>(ws, out, blocks, 1.0f / (float)B);
}

// Round 5
// 153.779 us; speedup vs baseline: 1.0507x; 1.0311x over previous
//
#include <hip/hip_runtime.h>

// RankingLoss: B=16384 rows, D=1024 fp32, C=14 int32 labels -> scalar fp32.
//
// Round 5: test the "global->VGPR return path is the per-CU wall" theory by
// switching the bulk traffic to the proven global_load_lds path (GEMM ladder
// sustains ~22 B/cy/CU through it vs our measured ~5.9 via global->VGPR).
// Block = 8 output rows; stages 9 zi + 9 zt row-slabs (1 KB each) per K-slab
// (SW=256 floats, 4 slabs) into double-buffered LDS (36 KB). Pipeline:
// issue next slab's 18 global_load_lds -> counted s_waitcnt vmcnt(5/4) (cur
// slab done, next stays in flight) -> raw s_barrier -> ds_read_b128 + dots
// -> __syncthreads (drain before buffer reuse; next-stage mostly landed by
// then). Wave w owns output rows 2w,2w+1. Margins via ballots in prologue,
// fully drained (vmcnt(0)) before staging so counted waits stay exact.
// XCD-bijective swizzle (2048 % 8 == 0). Deterministic 1-block phase2.

constexpr int D     = 1024;
constexpr int C     = 14;
constexpr int RPB   = 8;          // output rows per block
constexpr int NR    = RPB + 1;    // staged data rows per block
constexpr int SW    = 256;        // slab width in floats (1 KB)
constexpr int SLABS = D / SW;     // 4
constexpr int WPB   = 4;          // waves per block

__device__ __forceinline__ float dot4(const float4 x, const float4 y) {
    return x.x * y.x + x.y * y.y + x.z * y.z + x.w * y.w;
}

__device__ __forceinline__ void gl_lds16(const float* g, void* l) {
    __builtin_amdgcn_global_load_lds(
        (const __attribute__((address_space(1))) void*)g,
        (__attribute__((address_space(3))) void*)l, 16, 0, 0);
}

__global__ __launch_bounds__(256) void rank_phase1(
    const float* __restrict__ zi, const float* __restrict__ zt,
    const int* __restrict__ labels, float* __restrict__ partial, int B)
{
    const int wave = threadIdx.x >> 6;
    const int lane = threadIdx.x & 63;

    // Bijective XCD swizzle (gridDim.x % 8 == 0).
    const int nwg = gridDim.x;
    const int wg  = (blockIdx.x & 7) * (nwg >> 3) + (blockIdx.x >> 3);
    const int r0  = wg * RPB;
    const int M   = B - 1;  // B is a power of two

    // lbuf[dbuf][0..NR-1]=zi rows, [NR..2NR-1]=zt rows; 1 KB per row-slab.
    __shared__ float lbuf[2][2 * NR][SW];
    __shared__ float mlds[RPB];
    __shared__ float red[WPB];

    // ---- margins: waves 0,1 each cover 4 rows via 2 ballots ----
    if (wave < 2) {
        const int kk = lane >> 4, c = lane & 15;
        int lx = 0, lo = 0;
        if (c < C) {
            const int ra = (r0 + 4 * wave + kk) & M;
            const int rb = (ra + 1) & M;
            const int li = labels[(size_t)ra * C + c];
            const int lj = labels[(size_t)rb * C + c];
            lx = li ^ lj;
            lo = li | lj;
        }
        const unsigned long long bx = __ballot(lx != 0);
        const unsigned long long bo = __ballot(lo != 0);
        if (lane < 4) {
            const float dv = (float)__popcll((bx >> (16 * lane)) & 0x3FFFull);
            const float nv = (float)__popcll((bo >> (16 * lane)) & 0x3FFFull);
            mlds[4 * wave + lane] = (dv == 0.f) ? 0.f : fmaxf(0.5f, dv / nv);
        }
    }
    // Drain label loads + mlds ds_write so (a) counted vmcnt sees ONLY
    // staging ops, (b) mlds is LDS-visible before the first barrier.
    asm volatile("s_waitcnt vmcnt(0) lgkmcnt(0)" ::: "memory");
    __builtin_amdgcn_sched_barrier(0);

    // Per-wave staging ops: i = wave + 4t, t = 0..4 (waves 0,1: 5; 2,3: 4).
    // Precompute per-op per-lane global base pointers (row ptr + 16B*lane).
    const float* gsrc[5];
    #pragma unroll
    for (int t = 0; t < 5; ++t) {
        const int i = wave + WPB * t;
        if (i < 2 * NR) {
            const int    row = (i < NR) ? i : i - NR;
            const float* src = (i < NR) ? zi : zt;
            const int    rg  = (r0 + row) & M;
            gsrc[t] = src + (size_t)rg * D + 4 * lane;
        } else {
            gsrc[t] = nullptr;
        }
    }

    #define STAGE(s)                                                        \
        {                                                                   \
            const int _b = (s) & 1;                                         \
            _Pragma("unroll")                                               \
            for (int t = 0; t < 5; ++t) {                                   \
                const int i = wave + WPB * t;                               \
                if (i < 2 * NR)                                             \
                    gl_lds16(gsrc[t] + (s) * SW, &lbuf[_b][i][0]);          \
            }                                                               \
        }

    const int a = 2 * wave;  // local output rows a, a+1
    float p0 = 0.f, p1 = 0.f, i0 = 0.f, i1 = 0.f, t0 = 0.f, t1 = 0.f;

    STAGE(0);

    #pragma unroll
    for (int s = 0; s < SLABS; ++s) {
        if (s + 1 < SLABS) {
            STAGE(s + 1);
            // Current slab's stages done; next slab's stay in flight.
            if (wave < 2) asm volatile("s_waitcnt vmcnt(5)" ::: "memory");
            else          asm volatile("s_waitcnt vmcnt(4)" ::: "memory");
        } else {
            asm volatile("s_waitcnt vmcnt(0)" ::: "memory");
        }
        __builtin_amdgcn_s_barrier();       // all waves' cur stages done
        __builtin_amdgcn_sched_barrier(0);  // keep ds_reads below barrier

        const int b = s & 1;
        const float4 zia  = ((const float4*)lbuf[b][a])[lane];
        const float4 zia1 = ((const float4*)lbuf[b][a + 1])[lane];
        const float4 zia2 = ((const float4*)lbuf[b][a + 2])[lane];
        const float4 zta  = ((const float4*)lbuf[b][NR + a])[lane];
        const float4 zta1 = ((const float4*)lbuf[b][NR + a + 1])[lane];
        const float4 zta2 = ((const float4*)lbuf[b][NR + a + 2])[lane];

        p0 += dot4(zia,  zta);   // paired  row a
        i0 += dot4(zia1, zta);   // imp_img row a
        t0 += dot4(zta1, zia);   // imp_txt row a
        p1 += dot4(zia1, zta1);  // paired  row a+1
        i1 += dot4(zia2, zta1);  // imp_img row a+1
        t1 += dot4(zta2, zia1);  // imp_txt row a+1

        // Full barrier (drains everything) before buf[s&1] is overwritten
        // by STAGE(s+2) at the top of the next iteration. The next-slab
        // stages it drains have been flying under the compute above.
        __syncthreads();
    }
    #undef STAGE

    // Wave-reduce the 6 accumulators.
    #pragma unroll
    for (int off = 32; off > 0; off >>= 1) {
        p0 += __shfl_down(p0, off, 64);
        p1 += __shfl_down(p1, off, 64);
        i0 += __shfl_down(i0, off, 64);
        i1 += __shfl_down(i1, off, 64);
        t0 += __shfl_down(t0, off, 64);
        t1 += __shfl_down(t1, off, 64);
    }
    if (lane == 0) {
        const float m0 = mlds[a], m1 = mlds[a + 1];
        red[wave] = fmaxf(i0 - p0 + m0, 0.f) + fmaxf(t0 - p0 + m0, 0.f)
                  + fmaxf(i1 - p1 + m1, 0.f) + fmaxf(t1 - p1 + m1, 0.f);
    }
    __syncthreads();
    if (threadIdx.x == 0)
        partial[wg] = red[0] + red[1] + red[2] + red[3];
}

__global__ __launch_bounds__(256) void rank_phase2(
    const float* __restrict__ partial, float* __restrict__ out,
    int npart, float invB)
{
    float s = 0.f;
    for (int i = threadIdx.x; i < npart; i += 256) s += partial[i];
    #pragma unroll
    for (int off = 32; off > 0; off >>= 1) s += __shfl_down(s, off, 64);
    __shared__ float sm[4];
    if ((threadIdx.x & 63) == 0) sm[threadIdx.x >> 6] = s;
    __syncthreads();
    if (threadIdx.x == 0)
        out[0] = (sm[0] + sm[1] + sm[2] + sm[3]) * invB;
}

extern "C" void kernel_launch(void* const* d_in, const int* in_sizes, int n_in,
                              void* d_out, int out_size, void* d_ws, size_t ws_size,
                              hipStream_t stream) {
    const float* zi     = (const float*)d_in[0];
    const float* zt     = (const float*)d_in[1];
    const int*   labels = (const int*)d_in[2];
    float*       out    = (float*)d_out;
    float*       ws     = (float*)d_ws;

    const int B      = in_sizes[0] / D;  // 16384
    const int blocks = B / RPB;          // 2048

    rank_phase1<<<blocks, 256, 0, stream>>>(zi, zt, labels, ws, B);
    rank_phase2<<<1, 256, 0, stream>>>(ws, out, blocks, 1.0f / (float)B);
}

// Round 6
// 150.763 us; speedup vs baseline: 1.0717x; 1.0200x over previous
//
#include <hip/hip_runtime.h>

// RankingLoss: B=16384 rows, D=1024 fp32, C=14 int32 labels -> scalar fp32.
//
// Round 6: attack the measured invariant dur = FETCH_SIZE / ~1.45 TB/s.
// All 4 prior structures pinned at ~46 us because ~66 MB of L3-capacity
// misses are a random 64B-line scatter served at ~23% HBM efficiency.
// Fix under test: static cache partition. Rows in odd 16-row stripes
// (bit 4 of row index; 64 KB contiguous per tensor) are loaded with
// __builtin_nontemporal_load (nt flag: evict-first, no L3 retention) ->
// they stream from HBM as sequential bursts; even stripes (64 MB total)
// then fit in L3 and stay resident. Misses become streamy + predictable.
// Chassis = round-1 kernel verbatim (45.5 us A/B baseline): 4096 blocks,
// block = one 4-row group, 4 waves each own a D-quarter, single load batch,
// ballot margins, LDS cross-wave combine, XCD-bijective swizzle,
// deterministic 1-block phase2.

typedef float f32x4 __attribute__((ext_vector_type(4)));

constexpr int D   = 1024;
constexpr int C   = 14;
constexpr int RPB = 4;   // output rows per block (one 4-row group)
constexpr int WPB = 4;   // waves per block; wave w covers D-quarter w

__device__ __forceinline__ float dot4(const f32x4 x, const f32x4 y) {
    return x.x * y.x + x.y * y.y + x.z * y.z + x.w * y.w;
}

// nt is wave-uniform (derived from row index) -> cheap uniform branch.
__device__ __forceinline__ f32x4 ld4(const f32x4* __restrict__ p, bool nt) {
    return nt ? __builtin_nontemporal_load(p) : *p;
}

__global__ __launch_bounds__(256) void rank_phase1(
    const float* __restrict__ zi, const float* __restrict__ zt,
    const int* __restrict__ labels, float* __restrict__ partial, int B)
{
    const int wave = threadIdx.x >> 6;
    const int lane = threadIdx.x & 63;

    // Bijective XCD swizzle (gridDim.x % 8 == 0).
    const int nwg = gridDim.x;
    const int wg  = (blockIdx.x & 7) * (nwg >> 3) + (blockIdx.x >> 3);

    const int r0 = wg * RPB;
    const int M  = B - 1;               // B is a power of two
    const int idx = (wave << 6) + lane; // float4 index: wave w = quarter w

    // Early label loads (wave 0 only); ballots consumed before the combine.
    int lx = 0, lo = 0;
    {
        const int kk = lane >> 4, c = lane & 15;
        if (wave == 0 && c < C) {
            const int ra = (r0 + kk)     & M;
            const int rb = (r0 + kk + 1) & M;
            const int li = labels[(size_t)ra * C + c];
            const int lj = labels[(size_t)rb * C + c];
            lx = li ^ lj;
            lo = li | lj;
        }
    }

    // Batch ALL 10 loads (5 rows x 2 tensors, one quarter each), then dots.
    // NT policy per row: odd 16-row stripes stream (nt), even stripes cache.
    f32x4 a[RPB + 1], b[RPB + 1];
    #pragma unroll
    for (int k = 0; k <= RPB; ++k) {
        const int  r  = (r0 + k) & M;
        const bool nt = ((r >> 4) & 1) != 0;
        a[k] = ld4((const f32x4*)(zi + (size_t)r * D) + idx, nt);
        b[k] = ld4((const f32x4*)(zt + (size_t)r * D) + idx, nt);
    }

    float v[12];
    #pragma unroll
    for (int k = 0; k < RPB; ++k) {
        v[k]     = dot4(a[k],     b[k]);      // paired   dot(zi[k],  zt[k])
        v[4 + k] = dot4(a[k + 1], b[k]);      // imp_img  dot(zi[k+1],zt[k])
        v[8 + k] = dot4(b[k + 1], a[k]);      // imp_txt  dot(zt[k+1],zi[k])
    }

    // Wave-reduce the 12 quarter-dot partials.
    #pragma unroll
    for (int off = 32; off > 0; off >>= 1) {
        #pragma unroll
        for (int i = 0; i < 12; ++i) v[i] += __shfl_down(v[i], off, 64);
    }

    __shared__ float red[WPB][12];
    if (lane == 0) {
        #pragma unroll
        for (int i = 0; i < 12; ++i) red[wave][i] = v[i];
    }
    __syncthreads();

    if (wave == 0) {
        const unsigned long long bx = __ballot(lx != 0);
        const unsigned long long bo = __ballot(lo != 0);
        if (lane == 0) {
            float local = 0.f;
            #pragma unroll
            for (int k = 0; k < RPB; ++k) {
                const float p  = red[0][k]     + red[1][k]     + red[2][k]     + red[3][k];
                const float di = red[0][4 + k] + red[1][4 + k] + red[2][4 + k] + red[3][4 + k];
                const float dt = red[0][8 + k] + red[1][8 + k] + red[2][8 + k] + red[3][8 + k];
                const float dv = (float)__popcll((bx >> (16 * k)) & 0x3FFFull);
                const float nv = (float)__popcll((bo >> (16 * k)) & 0x3FFFull);
                const float m  = (dv == 0.f) ? 0.f : fmaxf(0.5f, dv / nv);
                local += fmaxf(di - p + m, 0.f) + fmaxf(dt - p + m, 0.f);
            }
            partial[wg] = local;
        }
    }
}

__global__ __launch_bounds__(256) void rank_phase2(
    const float* __restrict__ partial, float* __restrict__ out,
    int npart, float invB)
{
    float s = 0.f;
    for (int i = threadIdx.x; i < npart; i += 256) s += partial[i];
    #pragma unroll
    for (int off = 32; off > 0; off >>= 1) s += __shfl_down(s, off, 64);
    __shared__ float sm[4];
    if ((threadIdx.x & 63) == 0) sm[threadIdx.x >> 6] = s;
    __syncthreads();
    if (threadIdx.x == 0)
        out[0] = (sm[0] + sm[1] + sm[2] + sm[3]) * invB;
}

extern "C" void kernel_launch(void* const* d_in, const int* in_sizes, int n_in,
                              void* d_out, int out_size, void* d_ws, size_t ws_size,
                              hipStream_t stream) {
    const float* zi     = (const float*)d_in[0];
    const float* zt     = (const float*)d_in[1];
    const int*   labels = (const int*)d_in[2];
    float*       out    = (float*)d_out;
    float*       ws     = (float*)d_ws;

    const int B      = in_sizes[0] / D;  // 16384
    const int blocks = B / RPB;          // 4096

    rank_phase1<<<blocks, 256, 0, stream>>>(zi, zt, labels, ws, B);
    rank_phase2<<<1, 256, 0, stream>>>(ws, out, blocks, 1.0f / (float)B);
}